// Round 4
// baseline (2710.237 us; speedup 1.0000x reference)
//
#include <hip/hip_runtime.h>
#include <cstdint>
#include <cstddef>

#define D_MODEL 1024
#define D_STATE 16
#define E_DIM   2048
#define SEQ     4096
#define M_ROWS  16384

typedef unsigned short u16;
typedef unsigned int   u32;
typedef __attribute__((ext_vector_type(8))) short short8;   // 8 bf16 = 4 VGPRs
typedef __attribute__((ext_vector_type(4))) float f32x4;

__device__ __forceinline__ u16 f2bf(float f) {
    u32 u = __float_as_uint(f);
    u32 r = (u + 0x7fffu + ((u >> 16) & 1u)) >> 16;   // RNE
    return (u16)r;
}
__device__ __forceinline__ float bf2f(u16 h) {
    return __uint_as_float(((u32)h) << 16);
}

// async global->LDS, 16 B per lane. LDS dest is wave-uniform base + lane*16;
// our per-lane pointers are exactly that (linear in t), so this is well-formed.
__device__ __forceinline__ void gld_lds16(const void* g, void* l) {
    __builtin_amdgcn_global_load_lds(
        (__attribute__((address_space(1))) void*)(uintptr_t)g,
        (__attribute__((address_space(3))) void*)(uintptr_t)l,
        16, 0, 0);
}

// ---------------------------------------------------------------------------
// MFMA GEMM: C[M,N] = A[M,K] @ B[N,K]^T, A/B bf16 row-major (k-contiguous).
// 128x128 tile, BK=64, 4 waves (2x2 of 64x64), 4x4 16x16x32 MFMA per wave.
// m97-verified structure: UNSWIZZLED row-major LDS tiles [row][64], linear
// global_load_lds staging, frag reads ds_read_b128 at m*128+(quad+kk8)*16.
// (R3's XOR swizzle measured 1.7e8 bank conflicts / MfmaUtil 4.5% — removed.)
// MODE 0: out bf16 = acc + bias        (-> XP)
// MODE 1: gate: XC <- sigmoid(acc+bias) * (H@C^T + Dp*XC), bf16 in-place
// MODE 2: out fp32 = acc + bias        (-> final out)
// ---------------------------------------------------------------------------
#define BM 128
#define BN 128
#define BKS 64

union SMem {
    struct { u16 A[BM * BKS]; u16 B[BN * BKS]; } s;          // 16K + 16K
    struct { float H[BM * D_STATE]; float C[BN * D_STATE]; } e;
};

template <int MODE>
__global__ __launch_bounds__(256)
void mfma_gemm(const u16* __restrict__ Ag, const u16* __restrict__ Bg,
               int K, int Nst,
               const float* __restrict__ bias,
               u16* __restrict__ outb, float* __restrict__ outf,
               const float* __restrict__ Hm, const float* __restrict__ Cm,
               const float* __restrict__ Dp, u16* __restrict__ XC)
{
    __shared__ SMem sm;
    const int t     = threadIdx.x;
    const int lane  = t & 63;
    const int w     = t >> 6;
    const int col_l = lane & 15;
    const int quad  = lane >> 4;
    const int wm = (w & 1) * 64;
    const int wn = (w >> 1) * 64;
    const int bm = blockIdx.y * BM;
    const int bn = blockIdx.x * BN;

    // staging: chunk c = i*256 + t; row r = c>>3; col chunk q = c&7 (linear)
    const u16* pa[4]; const u16* pb[4]; int ldsOff[4];
#pragma unroll
    for (int i = 0; i < 4; ++i) {
        int c = i * 256 + t;
        int r = c >> 3;
        int q = c & 7;
        pa[i] = Ag + (size_t)(bm + r) * K + q * 8;
        pb[i] = Bg + (size_t)(bn + r) * K + q * 8;
        ldsOff[i] = c * 8;
    }

    f32x4 acc[4][4] = {};

    for (int k0 = 0; k0 < K; k0 += BKS) {
#pragma unroll
        for (int i = 0; i < 4; ++i) gld_lds16(pa[i] + k0, &sm.s.A[ldsOff[i]]);
#pragma unroll
        for (int i = 0; i < 4; ++i) gld_lds16(pb[i] + k0, &sm.s.B[ldsOff[i]]);
        __syncthreads();

#pragma unroll
        for (int kk8 = 0; kk8 < 8; kk8 += 4) {   // two K=32 MFMA steps
            short8 af[4], bfr[4];
#pragma unroll
            for (int i = 0; i < 4; ++i) {
                int m = wm + i * 16 + col_l;
                af[i] = *(const short8*)&sm.s.A[(m * 8 + quad + kk8) * 8];
            }
#pragma unroll
            for (int j = 0; j < 4; ++j) {
                int n = wn + j * 16 + col_l;
                bfr[j] = *(const short8*)&sm.s.B[(n * 8 + quad + kk8) * 8];
            }
#pragma unroll
            for (int i = 0; i < 4; ++i)
#pragma unroll
                for (int j = 0; j < 4; ++j)
                    acc[i][j] = __builtin_amdgcn_mfma_f32_16x16x32_bf16(
                        af[i], bfr[j], acc[i][j], 0, 0, 0);
        }
        __syncthreads();
    }

    // C/D layout: col = lane&15, row = quad*4 + reg   [verified m89/m91]
    if (MODE == 0) {
#pragma unroll
        for (int j = 0; j < 4; ++j) {
            int n = bn + wn + j * 16 + col_l;
            float bv = bias[n];
#pragma unroll
            for (int i = 0; i < 4; ++i) {
                int mb = bm + wm + i * 16 + quad * 4;
#pragma unroll
                for (int p = 0; p < 4; ++p)
                    outb[(size_t)(mb + p) * Nst + n] = f2bf(acc[i][j][p] + bv);
            }
        }
    } else if (MODE == 1) {
        // stage H rows (this m-tile) and C rows (this n-tile)
        for (int idx = t; idx < BM * D_STATE; idx += 256)
            sm.e.H[idx] = Hm[(size_t)(bm + (idx >> 4)) * D_STATE + (idx & 15)];
        for (int idx = t; idx < BN * D_STATE; idx += 256)
            sm.e.C[idx] = Cm[(size_t)(bn + (idx >> 4)) * D_STATE + (idx & 15)];
        __syncthreads();
#pragma unroll
        for (int i = 0; i < 4; ++i) {
            int ml = wm + i * 16 + quad * 4;
#pragma unroll
            for (int p = 0; p < 4; ++p) {
                float hrow[D_STATE];
#pragma unroll
                for (int s4 = 0; s4 < 4; ++s4)
                    *(f32x4*)&hrow[s4 * 4] = *(const f32x4*)&sm.e.H[(ml + p) * D_STATE + s4 * 4];
#pragma unroll
                for (int j = 0; j < 4; ++j) {
                    int nl = wn + j * 16 + col_l;
                    int n = bn + nl;
                    float z = acc[i][j][p] + bias[n];
                    float sig = 1.f / (1.f + __expf(-z));
                    float dot = 0.f;
#pragma unroll
                    for (int s = 0; s < D_STATE; ++s)
                        dot += hrow[s] * sm.e.C[nl * D_STATE + s];
                    size_t off = (size_t)(bm + ml + p) * Nst + n;
                    float xc = bf2f(XC[off]);
                    XC[off] = f2bf(sig * (dot + Dp[n] * xc));
                }
            }
        }
    } else {
#pragma unroll
        for (int j = 0; j < 4; ++j) {
            int n = bn + wn + j * 16 + col_l;
            float bv = bias[n];
#pragma unroll
            for (int i = 0; i < 4; ++i) {
                int mb = bm + wm + i * 16 + quad * 4;
#pragma unroll
                for (int p = 0; p < 4; ++p)
                    outf[(size_t)(mb + p) * Nst + n] = acc[i][j][p] + bv;
            }
        }
    }
}

// ---------------------------------------------------------------------------
// fp32 -> bf16 elementwise (8/thread)
// ---------------------------------------------------------------------------
__global__ __launch_bounds__(256)
void cvt_bf16_kernel(const float* __restrict__ in, u16* __restrict__ out, int n8)
{
    int idx = blockIdx.x * 256 + threadIdx.x;
    if (idx >= n8) return;
    const float4* p = (const float4*)(in + (size_t)idx * 8);
    float4 a = p[0], b = p[1];
    alignas(16) u16 o[8] = {f2bf(a.x), f2bf(a.y), f2bf(a.z), f2bf(a.w),
                            f2bf(b.x), f2bf(b.y), f2bf(b.z), f2bf(b.w)};
    *(short8*)(out + (size_t)idx * 8) = *(const short8*)o;
}

// ---------------------------------------------------------------------------
// transpose + convert: in [R,C] fp32 -> out [C,R] bf16. R, C % 64 == 0.
// ---------------------------------------------------------------------------
__global__ __launch_bounds__(256)
void transpose_bf16_kernel(const float* __restrict__ in, u16* __restrict__ out,
                           int R, int C)
{
    __shared__ float T[64][65];
    const int r0 = blockIdx.y * 64, c0 = blockIdx.x * 64;
    const int t = threadIdx.x;
#pragma unroll
    for (int p = 0; p < 4; ++p) {
        int rr = p * 16 + (t >> 4);
        int cc = (t & 15) * 4;
        *(float4*)&T[rr][cc] = *(const float4*)&in[(size_t)(r0 + rr) * C + c0 + cc];
    }
    __syncthreads();
#pragma unroll
    for (int q = 0; q < 2; ++q) {
        int oc = q * 32 + (t >> 3);
        int orow = (t & 7) * 8;
        alignas(16) u16 o[8];
#pragma unroll
        for (int j = 0; j < 8; ++j) o[j] = f2bf(T[orow + j][oc]);
        *(short8*)&out[(size_t)(c0 + oc) * R + r0 + orow] = *(const short8*)o;
    }
}

// ---------------------------------------------------------------------------
// causal depthwise conv (taps=4), bf16 in/out
// ---------------------------------------------------------------------------
__global__ __launch_bounds__(256)
void conv_kernel(const u16* __restrict__ XP, const float* __restrict__ conv_w,
                 const float* __restrict__ conv_b, u16* __restrict__ XC)
{
    const int m = blockIdx.x;
    const int l = m & (SEQ - 1);
    const int e8 = threadIdx.x * 8;
    float accv[8];
    {
        float4 c0 = *(const float4*)&conv_b[e8];
        float4 c1 = *(const float4*)&conv_b[e8 + 4];
        accv[0] = c0.x; accv[1] = c0.y; accv[2] = c0.z; accv[3] = c0.w;
        accv[4] = c1.x; accv[5] = c1.y; accv[6] = c1.z; accv[7] = c1.w;
    }
#pragma unroll
    for (int k = 0; k < 4; ++k) {
        if (l - 3 + k >= 0) {
            const short8 xv = *(const short8*)&XP[(size_t)(m - 3 + k) * E_DIM + e8];
#pragma unroll
            for (int j = 0; j < 8; ++j)
                accv[j] += bf2f((u16)xv[j]) * conv_w[(size_t)(e8 + j) * 4 + k];
        }
    }
    alignas(16) u16 o[8];
#pragma unroll
    for (int j = 0; j < 8; ++j) o[j] = f2bf(accv[j]);
    *(short8*)&XC[(size_t)m * E_DIM + e8] = *(const short8*)o;
}

// ---------------------------------------------------------------------------
// U[m,s] = sum_e bf2f(XC[m,e]) * A[e,s]   (fp32 accumulate)
// ---------------------------------------------------------------------------
__global__ __launch_bounds__(256)
void u_kernel(const u16* __restrict__ XC, const float* __restrict__ Amat,
              float* __restrict__ U)
{
    __shared__ __align__(16) u16 row[E_DIM];
    __shared__ float part[256];
    const int m = blockIdx.x, t = threadIdx.x;
    *(short8*)&row[t * 8] = *(const short8*)&XC[(size_t)m * E_DIM + t * 8];
    __syncthreads();
    const int s = t & 15, c = t >> 4;
    float acc = 0.f;
    for (int e = c * 128; e < (c + 1) * 128; ++e)
        acc += bf2f(row[e]) * Amat[(size_t)e * D_STATE + s];
    part[t] = acc;
    __syncthreads();
    if (t < 16) {
        float sum = 0.f;
#pragma unroll
        for (int cc = 0; cc < 16; ++cc) sum += part[cc * 16 + t];
        U[(size_t)m * D_STATE + t] = sum;
    }
}

// ---------------------------------------------------------------------------
// sequential scan: h_l = tanh(U_l + h_{l-1}), 64 independent (b,s) chains
// ---------------------------------------------------------------------------
__global__ __launch_bounds__(64)
void scan_kernel(const float* __restrict__ U, float* __restrict__ H)
{
    const int t = threadIdx.x;
    const int b = t >> 4;
    const int s = t & 15;
    const float* u = U + (size_t)b * SEQ * D_STATE + s;
    float*       h = H + (size_t)b * SEQ * D_STATE + s;

    float hv = 0.f;
    float unext = u[0];
    for (int l = 0; l < SEQ; ++l) {
        float ucur = unext;
        if (l + 1 < SEQ) unext = u[(size_t)(l + 1) * D_STATE];
        float ex = __expf(2.f * (ucur + hv));
        hv = 1.f - 2.f / (ex + 1.f);
        h[(size_t)l * D_STATE] = hv;
    }
}

// ---------------------------------------------------------------------------
extern "C" void kernel_launch(void* const* d_in, const int* in_sizes, int n_in,
                              void* d_out, int out_size, void* d_ws, size_t ws_size,
                              hipStream_t stream)
{
    const float* x      = (const float*)d_in[0];
    const float* W_in   = (const float*)d_in[1];
    const float* b_in   = (const float*)d_in[2];
    const float* conv_w = (const float*)d_in[3];
    const float* conv_b = (const float*)d_in[4];
    const float* Amat   = (const float*)d_in[5];
    const float* Cmat   = (const float*)d_in[6];
    const float* Dp     = (const float*)d_in[7];
    const float* W_out  = (const float*)d_in[8];
    const float* b_out  = (const float*)d_in[9];
    float* out = (float*)d_out;

    // workspace layout (115.3 MB total; 136 MB proven safe)
    char* ws = (char*)d_ws;
    u16*   xb     = (u16*)(ws);                                  // 33.55 MB
    u16*   W_inT  = (u16*)(ws + 33554432);                       //  8.39 MB
    u16*   W_outT = (u16*)(ws + 41943040);                       //  4.19 MB
    u16*   XC     = (u16*)(ws + 46137344);                       // 67.11 MB
    float* U      = (float*)(ws + 113246208);                    //  1.05 MB
    float* H      = (float*)(ws + 114294784);                    //  1.05 MB
    u16*   XP     = (u16*)d_out;  // x_proj bf16 lives in d_out (67.1 MB), dead after conv

    // 1) convert inputs to bf16 (weights transposed to [N,K])
    cvt_bf16_kernel<<<(M_ROWS * D_MODEL / 8 + 255) / 256, 256, 0, stream>>>(
        x, xb, M_ROWS * D_MODEL / 8);
    transpose_bf16_kernel<<<dim3((2 * E_DIM) / 64, D_MODEL / 64), 256, 0, stream>>>(
        W_in, W_inT, D_MODEL, 2 * E_DIM);
    transpose_bf16_kernel<<<dim3(D_MODEL / 64, E_DIM / 64), 256, 0, stream>>>(
        W_out, W_outT, E_DIM, D_MODEL);

    // 2) XP = bf16(xb @ W_inT[0:2048]^T + b_in)
    mfma_gemm<0><<<dim3(E_DIM / BN, M_ROWS / BM), 256, 0, stream>>>(
        xb, W_inT, D_MODEL, E_DIM, b_in, XP, nullptr, nullptr, nullptr, nullptr, nullptr);

    // 3) XC = bf16(causal_conv(XP) + conv_b)
    conv_kernel<<<M_ROWS, 256, 0, stream>>>(XP, conv_w, conv_b, XC);

    // 4) U = XC @ A ; 5) scan -> H
    u_kernel<<<M_ROWS, 256, 0, stream>>>(XC, Amat, U);
    scan_kernel<<<1, 64, 0, stream>>>(U, H);

    // 6) XC <- sigmoid(xb @ W_inT[2048:]^T + b_in[2048:]) * (H@C^T + Dp*XC)
    mfma_gemm<1><<<dim3(E_DIM / BN, M_ROWS / BM), 256, 0, stream>>>(
        xb, W_inT + (size_t)E_DIM * D_MODEL, D_MODEL, E_DIM, b_in + E_DIM,
        nullptr, nullptr, H, Cmat, Dp, XC);

    // 7) out = XC @ W_outT^T + b_out   (fp32)
    mfma_gemm<2><<<dim3(D_MODEL / BN, M_ROWS / BM), 256, 0, stream>>>(
        XC, W_outT, E_DIM, D_MODEL, b_out, nullptr, out, nullptr, nullptr, nullptr, nullptr);
}

// Round 5
// 1606.198 us; speedup vs baseline: 1.6874x; 1.6874x over previous
//
#include <hip/hip_runtime.h>
#include <cstdint>
#include <cstddef>

#define D_MODEL 1024
#define D_STATE 16
#define E_DIM   2048
#define SEQ     4096
#define M_ROWS  16384

typedef unsigned short u16;
typedef unsigned int   u32;
typedef __attribute__((ext_vector_type(8))) short short8;   // 8 bf16 = 4 VGPRs
typedef __attribute__((ext_vector_type(4))) float f32x4;

__device__ __forceinline__ u16 f2bf(float f) {
    u32 u = __float_as_uint(f);
    u32 r = (u + 0x7fffu + ((u >> 16) & 1u)) >> 16;   // RNE
    return (u16)r;
}
__device__ __forceinline__ float bf2f(u16 h) {
    return __uint_as_float(((u32)h) << 16);
}

// async global->LDS, 16 B per lane. LDS dest is wave-uniform base + lane*16.
__device__ __forceinline__ void gld_lds16(const void* g, void* l) {
    __builtin_amdgcn_global_load_lds(
        (__attribute__((address_space(1))) void*)(uintptr_t)g,
        (__attribute__((address_space(3))) void*)(uintptr_t)l,
        16, 0, 0);
}

// ---------------------------------------------------------------------------
// MFMA GEMM: C[M,N] = A[M,K] @ B[N,K]^T, A/B bf16 row-major (k-contiguous).
// 128x128 tile, BK=64, 4 waves (2x2 of 64x64), 4x4 16x16x32 MFMA per wave.
//
// FRAGMENT-ORDERED LDS (the m97 pattern): each 16-row x 32-k subtile is
// stored as 64 contiguous 16-B units in lane order (unit ell holds
// A[m=ell&15][k = (ell>>4)*8 .. +7]).  Every frag ds_read_b128 is then
// uniform_base + lane*16 -- the same conflict-free pattern as the linear
// global_load_lds staging.  (R3 XOR-swizzle: 1.7e8 conflicts; R4 row-major:
// 3.7e8 conflicts, 128-B row stride nukes the m-bits from the bank index.)
//
// LDS A index: unit block (msub 0..7, step 0..1) at ((msub*2+step)*64)*8 u16.
// MODE 0: out bf16 = acc + bias        (-> XP)
// MODE 1: gate: XC <- sigmoid(acc+bias) * (H@C^T + Dp*XC), bf16 in-place
// MODE 2: out fp32 = acc + bias        (-> final out)
// ---------------------------------------------------------------------------
#define BM 128
#define BN 128
#define BKS 64
#define HC_STR 17   // padded float stride for epilogue H/C tiles

union __align__(16) SMem {
    struct { u16 A[BM * BKS]; u16 B[BN * BKS]; } s;            // 16K + 16K
    struct { float H[BM * HC_STR]; float C[BN * HC_STR]; } e;  // 8.5K + 8.5K
};

template <int MODE>
__global__ __launch_bounds__(256)
void mfma_gemm(const u16* __restrict__ Ag, const u16* __restrict__ Bg,
               int K, int Nst,
               const float* __restrict__ bias,
               u16* __restrict__ outb, float* __restrict__ outf,
               const float* __restrict__ Hm, const float* __restrict__ Cm,
               const float* __restrict__ Dp, u16* __restrict__ XC)
{
    __shared__ SMem sm;
    const int t     = threadIdx.x;
    const int lane  = t & 63;
    const int w     = t >> 6;
    const int col_l = lane & 15;
    const int quad  = lane >> 4;
    const int wm = (w & 1) * 64;
    const int wn = (w >> 1) * 64;
    const int bm = blockIdx.y * BM;
    const int bn = blockIdx.x * BN;

    // staging: chunk c = i*256+t -> (msub = c>>7, step = (c>>6)&1, ell = c&63)
    // global src: row = msub*16 + (ell&15), 16B-chunk col = step*4 + (ell>>4)
    // LDS dest: c*16 bytes (linear; wave-uniform base + lane*16)
    const u16* pa[4]; const u16* pb[4]; int ldsOff[4];
#pragma unroll
    for (int i = 0; i < 4; ++i) {
        int c    = i * 256 + t;
        int msub = c >> 7;
        int step = (c >> 6) & 1;
        int ell  = c & 63;
        int row  = msub * 16 + (ell & 15);
        int c16  = step * 4 + (ell >> 4);
        pa[i] = Ag + (size_t)(bm + row) * K + c16 * 8;
        pb[i] = Bg + (size_t)(bn + row) * K + c16 * 8;
        ldsOff[i] = c * 8;
    }

    f32x4 acc[4][4] = {};

    for (int k0 = 0; k0 < K; k0 += BKS) {
#pragma unroll
        for (int i = 0; i < 4; ++i) gld_lds16(pa[i] + k0, &sm.s.A[ldsOff[i]]);
#pragma unroll
        for (int i = 0; i < 4; ++i) gld_lds16(pb[i] + k0, &sm.s.B[ldsOff[i]]);
        __syncthreads();

#pragma unroll
        for (int step = 0; step < 2; ++step) {   // two K=32 MFMA steps
            short8 af[4], bfr[4];
#pragma unroll
            for (int i = 0; i < 4; ++i) {
                int msub = (w & 1) * 4 + i;
                af[i] = *(const short8*)&sm.s.A[((msub * 2 + step) * 64 + lane) * 8];
            }
#pragma unroll
            for (int j = 0; j < 4; ++j) {
                int nsub = (w >> 1) * 4 + j;
                bfr[j] = *(const short8*)&sm.s.B[((nsub * 2 + step) * 64 + lane) * 8];
            }
#pragma unroll
            for (int i = 0; i < 4; ++i)
#pragma unroll
                for (int j = 0; j < 4; ++j)
                    acc[i][j] = __builtin_amdgcn_mfma_f32_16x16x32_bf16(
                        af[i], bfr[j], acc[i][j], 0, 0, 0);
        }
        __syncthreads();
    }

    // C/D layout: col = lane&15, row = quad*4 + reg   [verified m89/m91]
    if (MODE == 0) {
#pragma unroll
        for (int j = 0; j < 4; ++j) {
            int n = bn + wn + j * 16 + col_l;
            float bv = bias[n];
#pragma unroll
            for (int i = 0; i < 4; ++i) {
                int mb = bm + wm + i * 16 + quad * 4;
#pragma unroll
                for (int p = 0; p < 4; ++p)
                    outb[(size_t)(mb + p) * Nst + n] = f2bf(acc[i][j][p] + bv);
            }
        }
    } else if (MODE == 1) {
        // stage H rows (this m-tile) and C rows (this n-tile), padded stride
        for (int idx = t; idx < BM * D_STATE; idx += 256)
            sm.e.H[(idx >> 4) * HC_STR + (idx & 15)] =
                Hm[(size_t)(bm + (idx >> 4)) * D_STATE + (idx & 15)];
        for (int idx = t; idx < BN * D_STATE; idx += 256)
            sm.e.C[(idx >> 4) * HC_STR + (idx & 15)] =
                Cm[(size_t)(bn + (idx >> 4)) * D_STATE + (idx & 15)];
        __syncthreads();
#pragma unroll
        for (int i = 0; i < 4; ++i) {
            int ml = wm + i * 16 + quad * 4;
#pragma unroll
            for (int p = 0; p < 4; ++p) {
                float hrow[D_STATE];
#pragma unroll
                for (int s = 0; s < D_STATE; ++s)
                    hrow[s] = sm.e.H[(ml + p) * HC_STR + s];
#pragma unroll
                for (int j = 0; j < 4; ++j) {
                    int nl = wn + j * 16 + col_l;
                    int n = bn + nl;
                    float z = acc[i][j][p] + bias[n];
                    float sig = 1.f / (1.f + __expf(-z));
                    float dot = 0.f;
#pragma unroll
                    for (int s = 0; s < D_STATE; ++s)
                        dot += hrow[s] * sm.e.C[nl * HC_STR + s];
                    size_t off = (size_t)(bm + ml + p) * Nst + n;
                    float xc = bf2f(XC[off]);
                    XC[off] = f2bf(sig * (dot + Dp[n] * xc));
                }
            }
        }
    } else {
#pragma unroll
        for (int j = 0; j < 4; ++j) {
            int n = bn + wn + j * 16 + col_l;
            float bv = bias[n];
#pragma unroll
            for (int i = 0; i < 4; ++i) {
                int mb = bm + wm + i * 16 + quad * 4;
#pragma unroll
                for (int p = 0; p < 4; ++p)
                    outf[(size_t)(mb + p) * Nst + n] = acc[i][j][p] + bv;
            }
        }
    }
}

// ---------------------------------------------------------------------------
// fp32 -> bf16 elementwise (8/thread)
// ---------------------------------------------------------------------------
__global__ __launch_bounds__(256)
void cvt_bf16_kernel(const float* __restrict__ in, u16* __restrict__ out, int n8)
{
    int idx = blockIdx.x * 256 + threadIdx.x;
    if (idx >= n8) return;
    const float4* p = (const float4*)(in + (size_t)idx * 8);
    float4 a = p[0], b = p[1];
    alignas(16) u16 o[8] = {f2bf(a.x), f2bf(a.y), f2bf(a.z), f2bf(a.w),
                            f2bf(b.x), f2bf(b.y), f2bf(b.z), f2bf(b.w)};
    *(short8*)(out + (size_t)idx * 8) = *(const short8*)o;
}

// ---------------------------------------------------------------------------
// transpose + convert: in [R,C] fp32 -> out [C,R] bf16. R, C % 64 == 0.
// ---------------------------------------------------------------------------
__global__ __launch_bounds__(256)
void transpose_bf16_kernel(const float* __restrict__ in, u16* __restrict__ out,
                           int R, int C)
{
    __shared__ float T[64][65];
    const int r0 = blockIdx.y * 64, c0 = blockIdx.x * 64;
    const int t = threadIdx.x;
#pragma unroll
    for (int p = 0; p < 4; ++p) {
        int rr = p * 16 + (t >> 4);
        int cc = (t & 15) * 4;
        *(float4*)&T[rr][cc] = *(const float4*)&in[(size_t)(r0 + rr) * C + c0 + cc];
    }
    __syncthreads();
#pragma unroll
    for (int q = 0; q < 2; ++q) {
        int oc = q * 32 + (t >> 3);
        int orow = (t & 7) * 8;
        alignas(16) u16 o[8];
#pragma unroll
        for (int j = 0; j < 8; ++j) o[j] = f2bf(T[orow + j][oc]);
        *(short8*)&out[(size_t)(c0 + oc) * R + r0 + orow] = *(const short8*)o;
    }
}

// ---------------------------------------------------------------------------
// causal depthwise conv (taps=4), bf16 in/out
// ---------------------------------------------------------------------------
__global__ __launch_bounds__(256)
void conv_kernel(const u16* __restrict__ XP, const float* __restrict__ conv_w,
                 const float* __restrict__ conv_b, u16* __restrict__ XC)
{
    const int m = blockIdx.x;
    const int l = m & (SEQ - 1);
    const int e8 = threadIdx.x * 8;
    float accv[8];
    {
        float4 c0 = *(const float4*)&conv_b[e8];
        float4 c1 = *(const float4*)&conv_b[e8 + 4];
        accv[0] = c0.x; accv[1] = c0.y; accv[2] = c0.z; accv[3] = c0.w;
        accv[4] = c1.x; accv[5] = c1.y; accv[6] = c1.z; accv[7] = c1.w;
    }
#pragma unroll
    for (int k = 0; k < 4; ++k) {
        if (l - 3 + k >= 0) {
            const short8 xv = *(const short8*)&XP[(size_t)(m - 3 + k) * E_DIM + e8];
#pragma unroll
            for (int j = 0; j < 8; ++j)
                accv[j] += bf2f((u16)xv[j]) * conv_w[(size_t)(e8 + j) * 4 + k];
        }
    }
    alignas(16) u16 o[8];
#pragma unroll
    for (int j = 0; j < 8; ++j) o[j] = f2bf(accv[j]);
    *(short8*)&XC[(size_t)m * E_DIM + e8] = *(const short8*)o;
}

// ---------------------------------------------------------------------------
// U[m,s] = sum_e bf2f(XC[m,e]) * A[e,s]   (fp32 accumulate)
// ---------------------------------------------------------------------------
__global__ __launch_bounds__(256)
void u_kernel(const u16* __restrict__ XC, const float* __restrict__ Amat,
              float* __restrict__ U)
{
    __shared__ __align__(16) u16 row[E_DIM];
    __shared__ float part[256];
    const int m = blockIdx.x, t = threadIdx.x;
    *(short8*)&row[t * 8] = *(const short8*)&XC[(size_t)m * E_DIM + t * 8];
    __syncthreads();
    const int s = t & 15, c = t >> 4;
    float acc = 0.f;
    for (int e = c * 128; e < (c + 1) * 128; ++e)
        acc += bf2f(row[e]) * Amat[(size_t)e * D_STATE + s];
    part[t] = acc;
    __syncthreads();
    if (t < 16) {
        float sum = 0.f;
#pragma unroll
        for (int cc = 0; cc < 16; ++cc) sum += part[cc * 16 + t];
        U[(size_t)m * D_STATE + t] = sum;
    }
}

// ---------------------------------------------------------------------------
// sequential scan: h_l = tanh(U_l + h_{l-1}), 64 independent (b,s) chains
// ---------------------------------------------------------------------------
__global__ __launch_bounds__(64)
void scan_kernel(const float* __restrict__ U, float* __restrict__ H)
{
    const int t = threadIdx.x;
    const int b = t >> 4;
    const int s = t & 15;
    const float* u = U + (size_t)b * SEQ * D_STATE + s;
    float*       h = H + (size_t)b * SEQ * D_STATE + s;

    float hv = 0.f;
    float unext = u[0];
    for (int l = 0; l < SEQ; ++l) {
        float ucur = unext;
        if (l + 1 < SEQ) unext = u[(size_t)(l + 1) * D_STATE];
        float ex = __expf(2.f * (ucur + hv));
        hv = 1.f - 2.f / (ex + 1.f);
        h[(size_t)l * D_STATE] = hv;
    }
}

// ---------------------------------------------------------------------------
extern "C" void kernel_launch(void* const* d_in, const int* in_sizes, int n_in,
                              void* d_out, int out_size, void* d_ws, size_t ws_size,
                              hipStream_t stream)
{
    const float* x      = (const float*)d_in[0];
    const float* W_in   = (const float*)d_in[1];
    const float* b_in   = (const float*)d_in[2];
    const float* conv_w = (const float*)d_in[3];
    const float* conv_b = (const float*)d_in[4];
    const float* Amat   = (const float*)d_in[5];
    const float* Cmat   = (const float*)d_in[6];
    const float* Dp     = (const float*)d_in[7];
    const float* W_out  = (const float*)d_in[8];
    const float* b_out  = (const float*)d_in[9];
    float* out = (float*)d_out;

    // workspace layout (115.3 MB total; 136 MB proven safe)
    char* ws = (char*)d_ws;
    u16*   xb     = (u16*)(ws);                                  // 33.55 MB
    u16*   W_inT  = (u16*)(ws + 33554432);                       //  8.39 MB
    u16*   W_outT = (u16*)(ws + 41943040);                       //  4.19 MB
    u16*   XC     = (u16*)(ws + 46137344);                       // 67.11 MB
    float* U      = (float*)(ws + 113246208);                    //  1.05 MB
    float* H      = (float*)(ws + 114294784);                    //  1.05 MB
    u16*   XP     = (u16*)d_out;  // x_proj bf16 lives in d_out (67.1 MB), dead after conv

    // 1) convert inputs to bf16 (weights transposed to [N,K])
    cvt_bf16_kernel<<<(M_ROWS * D_MODEL / 8 + 255) / 256, 256, 0, stream>>>(
        x, xb, M_ROWS * D_MODEL / 8);
    transpose_bf16_kernel<<<dim3((2 * E_DIM) / 64, D_MODEL / 64), 256, 0, stream>>>(
        W_in, W_inT, D_MODEL, 2 * E_DIM);
    transpose_bf16_kernel<<<dim3(D_MODEL / 64, E_DIM / 64), 256, 0, stream>>>(
        W_out, W_outT, E_DIM, D_MODEL);

    // 2) XP = bf16(xb @ W_inT[0:2048]^T + b_in)
    mfma_gemm<0><<<dim3(E_DIM / BN, M_ROWS / BM), 256, 0, stream>>>(
        xb, W_inT, D_MODEL, E_DIM, b_in, XP, nullptr, nullptr, nullptr, nullptr, nullptr);

    // 3) XC = bf16(causal_conv(XP) + conv_b)
    conv_kernel<<<M_ROWS, 256, 0, stream>>>(XP, conv_w, conv_b, XC);

    // 4) U = XC @ A ; 5) scan -> H
    u_kernel<<<M_ROWS, 256, 0, stream>>>(XC, Amat, U);
    scan_kernel<<<1, 64, 0, stream>>>(U, H);

    // 6) XC <- sigmoid(xb @ W_inT[2048:]^T + b_in[2048:]) * (H@C^T + Dp*XC)
    mfma_gemm<1><<<dim3(E_DIM / BN, M_ROWS / BM), 256, 0, stream>>>(
        xb, W_inT + (size_t)E_DIM * D_MODEL, D_MODEL, E_DIM, b_in + E_DIM,
        nullptr, nullptr, H, Cmat, Dp, XC);

    // 7) out = XC @ W_outT^T + b_out   (fp32)
    mfma_gemm<2><<<dim3(D_MODEL / BN, M_ROWS / BM), 256, 0, stream>>>(
        XC, W_outT, E_DIM, D_MODEL, b_out, nullptr, out, nullptr, nullptr, nullptr, nullptr);
}